// Round 5
// baseline (640.993 us; speedup 1.0000x reference)
//
#include <hip/hip_runtime.h>
#include <math.h>

#define HIDDEN 8

// native clang vector — legal for __builtin_nontemporal_load/store
typedef unsigned u32x4 __attribute__((ext_vector_type(4)));

__device__ __forceinline__ unsigned pack_bf16_pair(float lo, float hi) {
    union { float f; unsigned u; } a, b;
    a.f = lo; b.f = hi;
    unsigned lr = (a.u + 0x7fffu + ((a.u >> 16) & 1u)) >> 16;          // rne
    unsigned hr = (b.u + 0x7fffu + ((b.u >> 16) & 1u)) & 0xffff0000u;  // rne
    return lr | hr;
}

// ---- precompute per-node partial pre-activations ------------------------
//   u[i] = zd[i] @ W1[0:8]          (8 fp32 -> 4 packed bf16 dwords)
//   v[i] = zm[i] @ W1[8:16] + b1    (8 fp32 -> 4 packed bf16 dwords)
__global__ __launch_bounds__(256) void precompute_uv_kernel(
    const float* __restrict__ zd, const float* __restrict__ zm,
    const float* __restrict__ w1, const float* __restrict__ b1,
    unsigned* __restrict__ u, unsigned* __restrict__ v, int N)
{
    int i = blockIdx.x * blockDim.x + threadIdx.x;
    if (i < N) {
        float x[HIDDEN];
#pragma unroll
        for (int k = 0; k < HIDDEN; ++k) x[k] = zd[i * HIDDEN + k];
        float acc[HIDDEN];
#pragma unroll
        for (int j = 0; j < HIDDEN; ++j) acc[j] = 0.0f;
#pragma unroll
        for (int k = 0; k < HIDDEN; ++k) {
#pragma unroll
            for (int j = 0; j < HIDDEN; ++j)
                acc[j] = fmaf(x[k], w1[k * HIDDEN + j], acc[j]);
        }
#pragma unroll
        for (int p = 0; p < 4; ++p)
            u[i * 4 + p] = pack_bf16_pair(acc[2 * p], acc[2 * p + 1]);
    } else if (i < 2 * N) {
        int q = i - N;
        float x[HIDDEN];
#pragma unroll
        for (int k = 0; k < HIDDEN; ++k) x[k] = zm[q * HIDDEN + k];
        float acc[HIDDEN];
#pragma unroll
        for (int j = 0; j < HIDDEN; ++j) acc[j] = b1[j];
#pragma unroll
        for (int k = 0; k < HIDDEN; ++k) {
#pragma unroll
            for (int j = 0; j < HIDDEN; ++j)
                acc[j] = fmaf(x[k], w1[(HIDDEN + k) * HIDDEN + j], acc[j]);
        }
#pragma unroll
        for (int p = 0; p < 4; ++p)
            v[q * 4 + p] = pack_bf16_pair(acc[2 * p], acc[2 * p + 1]);
    }
}

// ---- edge kernel: v0 structure, gathers as nt (L1 no-allocate) loads ----
// Each edge does two scattered 16B gathers into the 3.2 MB u/v tables.
// Random indices -> ~0% L1 hit; a normal load allocates+fills a 64B L1
// line per miss (4x L2->L1 fill amplification + per-miss tag/alloc cost).
// nt loads skip L1 allocation; tables stay L2-resident (3.2 MB < 4 MB/XCD).
__global__ __launch_bounds__(256) void edge_decoder_uv_kernel(
    const u32x4* __restrict__ u,   // [N] packed bf16 (8 vals, 16B)
    const u32x4* __restrict__ v,   // [N]
    const int* __restrict__ row, const int* __restrict__ col,
    const float* __restrict__ w2, const float* __restrict__ b2,
    float* __restrict__ out, int E, int N)
{
    int i = blockIdx.x * blockDim.x + threadIdx.x;
    if (i >= E) return;

    int r = row[i];
    int c = col[i];
    if (r < 0) r = 0;
    if (r > N - 1) r = N - 1;
    if (c < 0) c = 0;
    if (c > N - 1) c = N - 1;

    u32x4 pu = __builtin_nontemporal_load(u + r);
    u32x4 pv = __builtin_nontemporal_load(v + c);

    float logit = b2[0];
    unsigned q[4] = { pu.x, pu.y, pu.z, pu.w };
    unsigned s[4] = { pv.x, pv.y, pv.z, pv.w };
#pragma unroll
    for (int k = 0; k < 4; ++k) {
        union { unsigned q; float f; } a0, a1, b0, b1u;
        a0.q = q[k] << 16;
        a1.q = q[k] & 0xffff0000u;
        b0.q = s[k] << 16;
        b1u.q = s[k] & 0xffff0000u;
        float h0 = a0.f + b0.f;
        float h1 = a1.f + b1u.f;
        if (h0 < 0.0f) h0 = 0.0f;
        if (h1 < 0.0f) h1 = 0.0f;
        logit = fmaf(h0, w2[2 * k], logit);
        logit = fmaf(h1, w2[2 * k + 1], logit);
    }

    float o = 1.0f / (1.0f + expf(-logit));
    __builtin_nontemporal_store(o, out + i);
}

// ---- fallback: fp32 full MLP (only if workspace too small) --------------
__global__ __launch_bounds__(256) void edge_decoder_f32_kernel(
    const float* __restrict__ zd, const float* __restrict__ zm,
    const int* __restrict__ row, const int* __restrict__ col,
    const float* __restrict__ w1, const float* __restrict__ b1,
    const float* __restrict__ w2, const float* __restrict__ b2,
    float* __restrict__ out, int E, int N)
{
    int i = blockIdx.x * blockDim.x + threadIdx.x;
    if (i >= E) return;
    int r = row[i];
    int c = col[i];
    if (r < 0) r = 0;
    if (r > N - 1) r = N - 1;
    if (c < 0) c = 0;
    if (c > N - 1) c = N - 1;
    const float* zdr = zd + (size_t)r * HIDDEN;
    const float* zmc = zm + (size_t)c * HIDDEN;
    float z[16];
#pragma unroll
    for (int k = 0; k < HIDDEN; ++k) z[k] = zdr[k];
#pragma unroll
    for (int k = 0; k < HIDDEN; ++k) z[HIDDEN + k] = zmc[k];
    float h[HIDDEN];
#pragma unroll
    for (int j = 0; j < HIDDEN; ++j) h[j] = b1[j];
#pragma unroll
    for (int k = 0; k < 2 * HIDDEN; ++k) {
        float zk = z[k];
#pragma unroll
        for (int j = 0; j < HIDDEN; ++j)
            h[j] = fmaf(zk, w1[k * HIDDEN + j], h[j]);
    }
    float logit = b2[0];
#pragma unroll
    for (int j = 0; j < HIDDEN; ++j) {
        float hj = h[j] > 0.0f ? h[j] : 0.0f;
        logit = fmaf(hj, w2[j], logit);
    }
    out[i] = 1.0f / (1.0f + expf(-logit));
}

extern "C" void kernel_launch(void* const* d_in, const int* in_sizes, int n_in,
                              void* d_out, int out_size, void* d_ws, size_t ws_size,
                              hipStream_t stream) {
    const float* zd  = (const float*)d_in[0];
    const float* zm  = (const float*)d_in[1];
    const int*   eli = (const int*)d_in[2];   // [2, E] flat: row then col
    const float* w1  = (const float*)d_in[3];
    const float* b1  = (const float*)d_in[4];
    const float* w2  = (const float*)d_in[5];
    const float* b2  = (const float*)d_in[6];
    float* out = (float*)d_out;

    int E = out_size;                 // 16,000,000
    int N = in_sizes[0] / HIDDEN;     // 100,000
    if (E <= 0 || N <= 0) return;

    const int* row = eli;
    const int* col = eli + E;
    const int block = 256;

    size_t tbl_bytes = (size_t)N * 4 * sizeof(unsigned);   // 1.6 MB per table
    if (ws_size >= 2 * tbl_bytes) {
        unsigned* u = (unsigned*)d_ws;
        unsigned* v = u + (size_t)N * 4;

        int pgrid = (2 * N + block - 1) / block;
        precompute_uv_kernel<<<pgrid, block, 0, stream>>>(zd, zm, w1, b1, u, v, N);

        int grid = (E + block - 1) / block;
        edge_decoder_uv_kernel<<<grid, block, 0, stream>>>(
            (const u32x4*)u, (const u32x4*)v, row, col, w2, b2, out, E, N);
    } else {
        int grid = (E + block - 1) / block;
        edge_decoder_f32_kernel<<<grid, block, 0, stream>>>(
            zd, zm, row, col, w1, b1, w2, b2, out, E, N);
    }
}

// Round 6
// 313.073 us; speedup vs baseline: 2.0474x; 2.0474x over previous
//
#include <hip/hip_runtime.h>
#include <math.h>

#define HIDDEN 8

typedef int      i32x4 __attribute__((ext_vector_type(4)));
typedef float    f32x4 __attribute__((ext_vector_type(4)));

// Raw buffer load with cache-policy aux (bit0 = glc -> sc0 on CDNA3/4:
// bypass L1, still cached in L2). Declaration style proven in
// ROCm/composable_kernel (amd_buffer_addressing.hpp) — plain HIP, no asm text.
__device__ f32x4
llvm_amdgcn_raw_buffer_load_fp32x4(i32x4 srsrc, int voffset, int soffset, int aux)
    __asm("llvm.amdgcn.raw.buffer.load.v4f32");

__device__ __forceinline__ i32x4 make_srsrc(const void* base, unsigned bytes) {
    union { const void* p; unsigned w[2]; } a;
    a.p = base;
    i32x4 r;
    r.x = (int)a.w[0];                 // base[31:0]
    r.y = (int)(a.w[1] & 0xffffu);     // base[47:32], stride=0
    r.z = (int)bytes;                  // num_records (bytes, stride==0)
    r.w = 0x00020000;                  // raw untyped dword access
    return r;
}

__device__ __forceinline__ unsigned pack_bf16_pair(float lo, float hi) {
    union { float f; unsigned u; } a, b;
    a.f = lo; b.f = hi;
    unsigned lr = (a.u + 0x7fffu + ((a.u >> 16) & 1u)) >> 16;          // rne
    unsigned hr = (b.u + 0x7fffu + ((b.u >> 16) & 1u)) & 0xffff0000u;  // rne
    return lr | hr;
}

// ---- precompute per-node partial pre-activations ------------------------
//   u[i] = zd[i] @ W1[0:8]          (8 fp32 -> 4 packed bf16 dwords)
//   v[i] = zm[i] @ W1[8:16] + b1    (8 fp32 -> 4 packed bf16 dwords)
__global__ __launch_bounds__(256) void precompute_uv_kernel(
    const float* __restrict__ zd, const float* __restrict__ zm,
    const float* __restrict__ w1, const float* __restrict__ b1,
    unsigned* __restrict__ u, unsigned* __restrict__ v, int N)
{
    int i = blockIdx.x * blockDim.x + threadIdx.x;
    if (i < N) {
        float x[HIDDEN];
#pragma unroll
        for (int k = 0; k < HIDDEN; ++k) x[k] = zd[i * HIDDEN + k];
        float acc[HIDDEN];
#pragma unroll
        for (int j = 0; j < HIDDEN; ++j) acc[j] = 0.0f;
#pragma unroll
        for (int k = 0; k < HIDDEN; ++k) {
#pragma unroll
            for (int j = 0; j < HIDDEN; ++j)
                acc[j] = fmaf(x[k], w1[k * HIDDEN + j], acc[j]);
        }
#pragma unroll
        for (int p = 0; p < 4; ++p)
            u[i * 4 + p] = pack_bf16_pair(acc[2 * p], acc[2 * p + 1]);
    } else if (i < 2 * N) {
        int q = i - N;
        float x[HIDDEN];
#pragma unroll
        for (int k = 0; k < HIDDEN; ++k) x[k] = zm[q * HIDDEN + k];
        float acc[HIDDEN];
#pragma unroll
        for (int j = 0; j < HIDDEN; ++j) acc[j] = b1[j];
#pragma unroll
        for (int k = 0; k < HIDDEN; ++k) {
#pragma unroll
            for (int j = 0; j < HIDDEN; ++j)
                acc[j] = fmaf(x[k], w1[(HIDDEN + k) * HIDDEN + j], acc[j]);
        }
#pragma unroll
        for (int p = 0; p < 4; ++p)
            v[q * 4 + p] = pack_bf16_pair(acc[2 * p], acc[2 * p + 1]);
    }
}

// ---- edge kernel: v0 structure, gathers via sc0 buffer loads ------------
// 32M random 16B gathers into 3.2 MB tables: ~0% L1 hit; a normal load
// allocates+fills a 64B L1 line per miss and is throttled by the per-CU
// outstanding-miss queue (~64 deep x ~200cy L2 latency ~= the observed
// 159us floor). sc0 loads bypass L1 (no alloc, no fill, no miss-queue
// slot) but still hit in L2, where the tables are resident.
__global__ __launch_bounds__(256) void edge_decoder_uv_kernel(
    const unsigned* __restrict__ u,   // [N*4] packed bf16 pairs (16B/node)
    const unsigned* __restrict__ v,   // [N*4]
    const int* __restrict__ row, const int* __restrict__ col,
    const float* __restrict__ w2, const float* __restrict__ b2,
    float* __restrict__ out, int E, int N)
{
    int i = blockIdx.x * blockDim.x + threadIdx.x;
    if (i >= E) return;

    int r = row[i];
    int c = col[i];
    if (r < 0) r = 0;
    if (r > N - 1) r = N - 1;
    if (c < 0) c = 0;
    if (c > N - 1) c = N - 1;

    i32x4 srsrc_u = make_srsrc(u, (unsigned)N * 16u);
    i32x4 srsrc_v = make_srsrc(v, (unsigned)N * 16u);

    f32x4 fu = llvm_amdgcn_raw_buffer_load_fp32x4(srsrc_u, r * 16, 0, 1 /*sc0*/);
    f32x4 fv = llvm_amdgcn_raw_buffer_load_fp32x4(srsrc_v, c * 16, 0, 1 /*sc0*/);

    union { f32x4 f; unsigned w[4]; } cu, cv;
    cu.f = fu; cv.f = fv;

    float logit = b2[0];
#pragma unroll
    for (int k = 0; k < 4; ++k) {
        union { unsigned q; float f; } a0, a1, b0, b1u;
        a0.q = cu.w[k] << 16;
        a1.q = cu.w[k] & 0xffff0000u;
        b0.q = cv.w[k] << 16;
        b1u.q = cv.w[k] & 0xffff0000u;
        float h0 = a0.f + b0.f;
        float h1 = a1.f + b1u.f;
        if (h0 < 0.0f) h0 = 0.0f;
        if (h1 < 0.0f) h1 = 0.0f;
        logit = fmaf(h0, w2[2 * k], logit);
        logit = fmaf(h1, w2[2 * k + 1], logit);
    }

    out[i] = 1.0f / (1.0f + expf(-logit));
}

// ---- fallback: fp32 full MLP (only if workspace too small) --------------
__global__ __launch_bounds__(256) void edge_decoder_f32_kernel(
    const float* __restrict__ zd, const float* __restrict__ zm,
    const int* __restrict__ row, const int* __restrict__ col,
    const float* __restrict__ w1, const float* __restrict__ b1,
    const float* __restrict__ w2, const float* __restrict__ b2,
    float* __restrict__ out, int E, int N)
{
    int i = blockIdx.x * blockDim.x + threadIdx.x;
    if (i >= E) return;
    int r = row[i];
    int c = col[i];
    if (r < 0) r = 0;
    if (r > N - 1) r = N - 1;
    if (c < 0) c = 0;
    if (c > N - 1) c = N - 1;
    const float* zdr = zd + (size_t)r * HIDDEN;
    const float* zmc = zm + (size_t)c * HIDDEN;
    float z[16];
#pragma unroll
    for (int k = 0; k < HIDDEN; ++k) z[k] = zdr[k];
#pragma unroll
    for (int k = 0; k < HIDDEN; ++k) z[HIDDEN + k] = zmc[k];
    float h[HIDDEN];
#pragma unroll
    for (int j = 0; j < HIDDEN; ++j) h[j] = b1[j];
#pragma unroll
    for (int k = 0; k < 2 * HIDDEN; ++k) {
        float zk = z[k];
#pragma unroll
        for (int j = 0; j < HIDDEN; ++j)
            h[j] = fmaf(zk, w1[k * HIDDEN + j], h[j]);
    }
    float logit = b2[0];
#pragma unroll
    for (int j = 0; j < HIDDEN; ++j) {
        float hj = h[j] > 0.0f ? h[j] : 0.0f;
        logit = fmaf(hj, w2[j], logit);
    }
    out[i] = 1.0f / (1.0f + expf(-logit));
}

extern "C" void kernel_launch(void* const* d_in, const int* in_sizes, int n_in,
                              void* d_out, int out_size, void* d_ws, size_t ws_size,
                              hipStream_t stream) {
    const float* zd  = (const float*)d_in[0];
    const float* zm  = (const float*)d_in[1];
    const int*   eli = (const int*)d_in[2];   // [2, E] flat: row then col
    const float* w1  = (const float*)d_in[3];
    const float* b1  = (const float*)d_in[4];
    const float* w2  = (const float*)d_in[5];
    const float* b2  = (const float*)d_in[6];
    float* out = (float*)d_out;

    int E = out_size;                 // 16,000,000
    int N = in_sizes[0] / HIDDEN;     // 100,000
    if (E <= 0 || N <= 0) return;

    const int* row = eli;
    const int* col = eli + E;
    const int block = 256;

    size_t tbl_bytes = (size_t)N * 4 * sizeof(unsigned);   // 1.6 MB per table
    if (ws_size >= 2 * tbl_bytes) {
        unsigned* u = (unsigned*)d_ws;
        unsigned* v = u + (size_t)N * 4;

        int pgrid = (2 * N + block - 1) / block;
        precompute_uv_kernel<<<pgrid, block, 0, stream>>>(zd, zm, w1, b1, u, v, N);

        int grid = (E + block - 1) / block;
        edge_decoder_uv_kernel<<<grid, block, 0, stream>>>(
            u, v, row, col, w2, b2, out, E, N);
    } else {
        int grid = (E + block - 1) / block;
        edge_decoder_f32_kernel<<<grid, block, 0, stream>>>(
            zd, zm, row, col, w1, b1, w2, b2, out, E, N);
    }
}